// Round 9
// baseline (206.976 us; speedup 1.0000x reference)
//
#include <hip/hip_runtime.h>

typedef __attribute__((ext_vector_type(8))) short bf16x8;
typedef __attribute__((ext_vector_type(4))) float f32x4;
typedef __attribute__((ext_vector_type(4))) unsigned short u16x4;

#define HW_ 16384
#define LDSTR 144     // 72 bf16 elems * 2B per LDS row
#define TILEB 9216    // one 64-pixel x 64-channel bf16 tile

__device__ __forceinline__ float bf2f(unsigned short u) {
  union { unsigned u; float f; } x; x.u = ((unsigned)u) << 16; return x.f;
}
__device__ __forceinline__ unsigned short f2bf(float f) {
  union { float f; unsigned u; } x; x.f = f;
  unsigned r = x.u + 0x7fffu + ((x.u >> 16) & 1u);
  return (unsigned short)(r >> 16);
}
// XOR-swizzled LDS byte offset for transposed tile xT[px][ch]
__device__ __forceinline__ int swz(int row, int cb) {
  return row * LDSTR + (cb ^ (((row >> 3) & 7) << 4));
}

#define MFMA(a, b, c) __builtin_amdgcn_mfma_f32_16x16x32_bf16(a, b, c, 0, 0, 0)

// (256,4): R8 measured VGPR demand = 80, well under the 128-VGPR cap for
// 4 waves/SIMD — unlike R5 where demand ~190 forced under 128 caused the
// spill catastrophe. LDS 36864 B allows exactly 4 blocks/CU -> 50% occupancy.
__global__ __launch_bounds__(256, 4) void gci_kernel(
    const float* __restrict__ x1, const float* __restrict__ x2,
    const float* __restrict__ x3, const float* __restrict__ x4,
    const float* __restrict__ wI, const float* __restrict__ bI,
    const float* __restrict__ wS, const float* __restrict__ bS,
    const float* __restrict__ wG, const float* __restrict__ bG,
    float* __restrict__ out)
{
  // 4 tiles of [64 px][72 bf16]: xT0..xT3 (36864 B)
  __shared__ __align__(16) char ldsb[4 * TILEB];

  const int t    = threadIdx.x;
  const int lane = t & 63;
  const int w    = t >> 6;       // wave id == output-channel group (16 ch)
  const int lr   = lane & 15;
  const int lg   = lane >> 4;

  const int pix0 = blockIdx.x * 64;
  const int b    = pix0 >> 14;          // image index (HW = 16384)
  const int pimg = pix0 & (HW_ - 1);    // pixel offset within image

  const float* xin[4] = {x1, x2, x3, x4};

  // ---------- stage x1..x4 transposed (bf16) into LDS ----------
  #pragma unroll
  for (int ch2 = 0; ch2 < 4; ++ch2) {
    const int q  = ch2 * 256 + t;       // 1024 chunks: 64 ch x 16 px-quads
    const int c  = q >> 4;
    const int p4 = q & 15;
    const int goff = (b * 64 + c) * HW_ + pimg + p4 * 4;
    #pragma unroll
    for (int i = 0; i < 4; ++i) {
      f32x4 v = *reinterpret_cast<const f32x4*>(xin[i] + goff);
      #pragma unroll
      for (int j = 0; j < 4; ++j)
        *(unsigned short*)(ldsb + i * TILEB + swz(p4 * 4 + j, c * 2)) = f2bf(v[j]);
    }
  }

  // ---------- this wave's weights: 16 output channels (rows w*16..+15) ----------
  // A-frag(kk): lane holds W[w*16 + lr][kk*32 + lg*8 + j], j=0..7
  bf16x8 fWi[2], fD[2], fG1[2], fG2[2];
  #pragma unroll
  for (int kk = 0; kk < 2; ++kk) {
    const int row = w * 16 + lr, col = kk * 32 + lg * 8;
    f32x4 wa = *(const f32x4*)(wI + row * 64 + col);
    f32x4 wb = *(const f32x4*)(wI + row * 64 + col + 4);
    f32x4 sa = *(const f32x4*)(wS + row * 64 + col);
    f32x4 sb = *(const f32x4*)(wS + row * 64 + col + 4);
    f32x4 ga = *(const f32x4*)(wG + row * 128 + col);
    f32x4 gb = *(const f32x4*)(wG + row * 128 + col + 4);
    f32x4 ha = *(const f32x4*)(wG + row * 128 + 64 + col);
    f32x4 hb = *(const f32x4*)(wG + row * 128 + 64 + col + 4);
    #pragma unroll
    for (int j = 0; j < 4; ++j) {
      fWi[kk][j]     = (short)f2bf(wa[j]);
      fWi[kk][j + 4] = (short)f2bf(wb[j]);
      fD[kk][j]      = (short)f2bf(sa[j] - wa[j]);
      fD[kk][j + 4]  = (short)f2bf(sb[j] - wb[j]);
      fG1[kk][j]     = (short)f2bf(ga[j]);
      fG1[kk][j + 4] = (short)f2bf(gb[j]);
      fG2[kk][j]     = (short)f2bf(ha[j]);
      fG2[kk][j + 4] = (short)f2bf(hb[j]);
    }
  }

  // biases: C/D row = lg*4 + r  ->  ch = w*16 + lg*4 + r
  f32x4 biasA0, biasG;
  #pragma unroll
  for (int r = 0; r < 4; ++r) {
    const int ch = w * 16 + lg * 4 + r;
    biasA0[r] = bS[ch] + 3.f * bI[ch];
    biasG[r]  = bG[ch];
  }

  __syncthreads();

  // ---------- Abase[g] = W_inter * xsum + bias, all 4 px-groups ----------
  f32x4 Abase[4];
  #pragma unroll
  for (int g = 0; g < 4; ++g) {
    bf16x8 xs[2];
    #pragma unroll
    for (int kk = 0; kk < 2; ++kk) {
      float acc[8] = {0.f, 0.f, 0.f, 0.f, 0.f, 0.f, 0.f, 0.f};
      #pragma unroll
      for (int i = 0; i < 4; ++i) {
        bf16x8 f = *(const bf16x8*)(ldsb + i * TILEB + swz(g * 16 + lr, kk * 64 + lg * 16));
        #pragma unroll
        for (int j = 0; j < 8; ++j) acc[j] += bf2f((unsigned short)f[j]);
      }
      #pragma unroll
      for (int j = 0; j < 8; ++j) xs[kk][j] = (short)f2bf(acc[j]);
    }
    Abase[g] = biasA0;
    #pragma unroll
    for (int kk = 0; kk < 2; ++kk) Abase[g] = MFMA(fWi[kk], xs[kk], Abase[g]);
  }

  // ---------- per tensor ----------
  #pragma unroll
  for (int i = 0; i < 4; ++i) {
    char* tb = ldsb + i * TILEB;

    // B-frags for all 4 px-groups (held across agg AND gate; tile is overwritten)
    bf16x8 xB[4][2];
    #pragma unroll
    for (int g = 0; g < 4; ++g)
      #pragma unroll
      for (int kk = 0; kk < 2; ++kk)
        xB[g][kk] = *(const bf16x8*)(tb + swz(g * 16 + lr, kk * 64 + lg * 16));

    // residual pre-read: lane = px, channels (w*16+2j, w*16+2j+1)
    unsigned xrp[8];
    #pragma unroll
    for (int j = 0; j < 8; ++j)
      xrp[j] = *(const unsigned*)(tb + swz(lane, w * 32 + 4 * j));

    // agg = relu(D * x_i + Abase)
    f32x4 agg[4];
    #pragma unroll
    for (int g = 0; g < 4; ++g) {
      agg[g] = Abase[g];
      #pragma unroll
      for (int kk = 0; kk < 2; ++kk) agg[g] = MFMA(fD[kk], xB[g][kk], agg[g]);
    }

    __syncthreads();   // all waves done reading x-tile i

    // write relu(agg) bf16 over tile i: our 16 ch columns, all px rows
    #pragma unroll
    for (int g = 0; g < 4; ++g) {
      u16x4 pk;
      #pragma unroll
      for (int r = 0; r < 4; ++r) pk[r] = f2bf(fmaxf(agg[g][r], 0.f));
      *(u16x4*)(tb + swz(g * 16 + lr, w * 32 + lg * 8)) = pk;
    }

    __syncthreads();   // aggT complete (all 64 channels)

    // gate: out = x + Wg1*x + Wg2*agg + b_gate
    f32x4 og[4];
    #pragma unroll
    for (int g = 0; g < 4; ++g) {
      bf16x8 aB[2];
      #pragma unroll
      for (int kk = 0; kk < 2; ++kk)
        aB[kk] = *(const bf16x8*)(tb + swz(g * 16 + lr, kk * 64 + lg * 16));
      og[g] = biasG;
      #pragma unroll
      for (int kk = 0; kk < 2; ++kk) {
        og[g] = MFMA(fG1[kk], xB[g][kk], og[g]);
        og[g] = MFMA(fG2[kk], aB[kk], og[g]);
      }
    }

    // stores: redistribute so one instruction = 64 consecutive px (256 B lines)
    const int obase0 = i * 16777216 + b * 64 * HW_ + pimg;
    #pragma unroll
    for (int c = 0; c < 16; ++c) {
      const int r    = c & 3;
      const int srcl = ((c >> 2) << 4) | lr;   // lg group holding channel c
      float t0 = __shfl(og[0][r], srcl, 64);
      float t1 = __shfl(og[1][r], srcl, 64);
      float t2 = __shfl(og[2][r], srcl, 64);
      float t3 = __shfl(og[3][r], srcl, 64);
      float v = (lane < 16) ? t0 : (lane < 32) ? t1 : (lane < 48) ? t2 : t3;
      v += bf2f((unsigned short)(xrp[c >> 1] >> ((c & 1) * 16)));
      out[obase0 + (w * 16 + c) * HW_ + lane] = v;
    }
  }
}

extern "C" void kernel_launch(void* const* d_in, const int* in_sizes, int n_in,
                              void* d_out, int out_size, void* d_ws, size_t ws_size,
                              hipStream_t stream) {
  (void)in_sizes; (void)n_in; (void)d_ws; (void)ws_size; (void)out_size;
  gci_kernel<<<dim3(4096), dim3(256), 0, stream>>>(
      (const float*)d_in[0], (const float*)d_in[1],
      (const float*)d_in[2], (const float*)d_in[3],
      (const float*)d_in[4], (const float*)d_in[5],
      (const float*)d_in[6], (const float*)d_in[7],
      (const float*)d_in[8], (const float*)d_in[9],
      (float*)d_out);
}

// Round 11
// 143.915 us; speedup vs baseline: 1.4382x; 1.4382x over previous
//
#include <hip/hip_runtime.h>

typedef __attribute__((ext_vector_type(8))) short bf16x8;
typedef __attribute__((ext_vector_type(4))) float f32x4;
typedef __attribute__((ext_vector_type(4))) unsigned short u16x4;

#define HW_ 16384
#define LDSTR 128     // 64 bf16 elems * 2B, no pad (XOR swizzle instead)
#define TILEB 8192    // one 64-px x 64-ch bf16 tile
#define AGGB  32768   // 5th buffer: aggT

__device__ __forceinline__ float bf2f(unsigned short u) {
  union { unsigned u; float f; } x; x.u = ((unsigned)u) << 16; return x.f;
}
__device__ __forceinline__ unsigned short f2bf(float f) {
  union { float f; unsigned u; } x; x.f = f;
  unsigned r = x.u + 0x7fffu + ((x.u >> 16) & 1u);
  return (unsigned short)(r >> 16);
}
// XOR-swizzle: permutes 16-B groups within each 128-B row by row&7.
// All accesses (b64 writes, b128 frag reads, b32/b16 residual reads) use it.
__device__ __forceinline__ int swz(int row, int cb) {
  return row * LDSTR + (cb ^ ((row & 7) << 4));
}

#define MFMA(a, b, c) __builtin_amdgcn_mfma_f32_16x16x32_bf16(a, b, c, 0, 0, 0)

// (256,4): unified VGPR+AGPR demand reduced to ~110 by NOT holding xB/xrp
// across phases (x-tile stays intact; agg goes to a separate LDS buffer).
// R9 showed (256,4) with demand ~140 spills; this version fits the 128 cap.
__global__ __launch_bounds__(256, 4) void gci_kernel(
    const float* __restrict__ x1, const float* __restrict__ x2,
    const float* __restrict__ x3, const float* __restrict__ x4,
    const float* __restrict__ wI, const float* __restrict__ bI,
    const float* __restrict__ wS, const float* __restrict__ bS,
    const float* __restrict__ wG, const float* __restrict__ bG,
    float* __restrict__ out)
{
  // xT0..xT3 at i*TILEB, aggT at AGGB   (40960 B -> exactly 4 blocks/CU)
  __shared__ __align__(16) char ldsb[5 * TILEB];

  const int t    = threadIdx.x;
  const int lane = t & 63;
  const int w    = t >> 6;       // wave id == output-channel group (16 ch)
  const int lr   = lane & 15;
  const int lg   = lane >> 4;

  const int pix0 = blockIdx.x * 64;
  const int b    = pix0 >> 14;          // image index (HW = 16384)
  const int pimg = pix0 & (HW_ - 1);    // pixel offset within image

  const float* xin[4] = {x1, x2, x3, x4};

  // ---------- stage x1..x4 transposed (bf16) into LDS ----------
  // thread: 1 px (lane) x 4 consecutive channels (cq) -> one ds_write_b64
  #pragma unroll
  for (int k = 0; k < 4; ++k) {
    const int cq = k * 4 + w;                    // channel-quad 0..15
    const int gbase = (b * 64 + cq * 4) * HW_ + pimg + lane;
    #pragma unroll
    for (int i = 0; i < 4; ++i) {
      u16x4 pk;
      #pragma unroll
      for (int j = 0; j < 4; ++j) pk[j] = f2bf(xin[i][gbase + j * HW_]);
      *(u16x4*)(ldsb + i * TILEB + swz(lane, cq * 8)) = pk;
    }
  }

  // ---------- this wave's weights: 16 output channels (rows w*16..+15) ----------
  // A-frag(kk): lane holds W[w*16 + lr][kk*32 + lg*8 + j], j=0..7
  bf16x8 fWi[2], fD[2], fG1[2], fG2[2];
  #pragma unroll
  for (int kk = 0; kk < 2; ++kk) {
    const int row = w * 16 + lr, col = kk * 32 + lg * 8;
    f32x4 wa = *(const f32x4*)(wI + row * 64 + col);
    f32x4 wb = *(const f32x4*)(wI + row * 64 + col + 4);
    f32x4 sa = *(const f32x4*)(wS + row * 64 + col);
    f32x4 sb = *(const f32x4*)(wS + row * 64 + col + 4);
    f32x4 ga = *(const f32x4*)(wG + row * 128 + col);
    f32x4 gb = *(const f32x4*)(wG + row * 128 + col + 4);
    f32x4 ha = *(const f32x4*)(wG + row * 128 + 64 + col);
    f32x4 hb = *(const f32x4*)(wG + row * 128 + 64 + col + 4);
    #pragma unroll
    for (int j = 0; j < 4; ++j) {
      fWi[kk][j]     = (short)f2bf(wa[j]);
      fWi[kk][j + 4] = (short)f2bf(wb[j]);
      fD[kk][j]      = (short)f2bf(sa[j] - wa[j]);
      fD[kk][j + 4]  = (short)f2bf(sb[j] - wb[j]);
      fG1[kk][j]     = (short)f2bf(ga[j]);
      fG1[kk][j + 4] = (short)f2bf(gb[j]);
      fG2[kk][j]     = (short)f2bf(ha[j]);
      fG2[kk][j + 4] = (short)f2bf(hb[j]);
    }
  }

  // biases: C/D row = lg*4 + r  ->  ch = w*16 + lg*4 + r
  f32x4 biasA0, biasG;
  #pragma unroll
  for (int r = 0; r < 4; ++r) {
    const int ch = w * 16 + lg * 4 + r;
    biasA0[r] = bS[ch] + 3.f * bI[ch];
    biasG[r]  = bG[ch];
  }

  __syncthreads();

  // ---------- Abase[g] = W_inter * xsum + bias, all 4 px-groups ----------
  f32x4 Abase[4];
  #pragma unroll
  for (int g = 0; g < 4; ++g) {
    Abase[g] = biasA0;
    #pragma unroll
    for (int kk = 0; kk < 2; ++kk) {
      float acc[8] = {0.f, 0.f, 0.f, 0.f, 0.f, 0.f, 0.f, 0.f};
      #pragma unroll
      for (int i = 0; i < 4; ++i) {
        bf16x8 f = *(const bf16x8*)(ldsb + i * TILEB + swz(g * 16 + lr, kk * 64 + lg * 16));
        #pragma unroll
        for (int j = 0; j < 8; ++j) acc[j] += bf2f((unsigned short)f[j]);
      }
      bf16x8 xs;
      #pragma unroll
      for (int j = 0; j < 8; ++j) xs[j] = (short)f2bf(acc[j]);
      Abase[g] = MFMA(fWi[kk], xs, Abase[g]);
    }
  }

  // ---------- per tensor ----------
  #pragma unroll
  for (int i = 0; i < 4; ++i) {
    char* tb = ldsb + i * TILEB;
    char* ab = ldsb + AGGB;

    // agg = relu(D * x_i + Abase); x-frags read lazily (tile stays intact)
    f32x4 agg[4];
    #pragma unroll
    for (int g = 0; g < 4; ++g) {
      agg[g] = Abase[g];
      #pragma unroll
      for (int kk = 0; kk < 2; ++kk) {
        bf16x8 xb = *(const bf16x8*)(tb + swz(g * 16 + lr, kk * 64 + lg * 16));
        agg[g] = MFMA(fD[kk], xb, agg[g]);
      }
    }

    // write relu(agg) bf16 to aggT (our 16 ch columns, all px rows)
    #pragma unroll
    for (int g = 0; g < 4; ++g) {
      u16x4 pk;
      #pragma unroll
      for (int r = 0; r < 4; ++r) pk[r] = f2bf(fmaxf(agg[g][r], 0.f));
      *(u16x4*)(ab + swz(g * 16 + lr, w * 32 + lg * 8)) = pk;
    }

    __syncthreads();   // aggT complete (all 64 channels)

    // gate: out = x + Wg1*x + Wg2*agg + b_gate   (x-frags re-read from intact tile)
    f32x4 og[4];
    #pragma unroll
    for (int g = 0; g < 4; ++g) {
      og[g] = biasG;
      #pragma unroll
      for (int kk = 0; kk < 2; ++kk) {
        bf16x8 xb = *(const bf16x8*)(tb + swz(g * 16 + lr, kk * 64 + lg * 16));
        bf16x8 ag = *(const bf16x8*)(ab + swz(g * 16 + lr, kk * 64 + lg * 16));
        og[g] = MFMA(fG1[kk], xb, og[g]);
        og[g] = MFMA(fG2[kk], ag, og[g]);
      }
    }

    // residual (transient): lane = px, channel pair (w*16+2j, w*16+2j+1)
    unsigned xrp[8];
    #pragma unroll
    for (int j = 0; j < 8; ++j)
      xrp[j] = *(const unsigned*)(tb + swz(lane, w * 32 + 4 * j));

    // stores: redistribute so one instruction = 64 consecutive px (256 B lines)
    const int obase0 = i * 16777216 + b * 64 * HW_ + pimg;
    #pragma unroll
    for (int c = 0; c < 16; ++c) {
      const int r    = c & 3;
      const int srcl = ((c >> 2) << 4) | lr;   // lane group holding channel c
      float t0 = __shfl(og[0][r], srcl, 64);
      float t1 = __shfl(og[1][r], srcl, 64);
      float t2 = __shfl(og[2][r], srcl, 64);
      float t3 = __shfl(og[3][r], srcl, 64);
      float v = (lane < 16) ? t0 : (lane < 32) ? t1 : (lane < 48) ? t2 : t3;
      v += bf2f((unsigned short)(xrp[c >> 1] >> ((c & 1) * 16)));
      out[obase0 + (w * 16 + c) * HW_ + lane] = v;
    }

    __syncthreads();   // before next tensor overwrites aggT
  }
}

extern "C" void kernel_launch(void* const* d_in, const int* in_sizes, int n_in,
                              void* d_out, int out_size, void* d_ws, size_t ws_size,
                              hipStream_t stream) {
  (void)in_sizes; (void)n_in; (void)d_ws; (void)ws_size; (void)out_size;
  gci_kernel<<<dim3(4096), dim3(256), 0, stream>>>(
      (const float*)d_in[0], (const float*)d_in[1],
      (const float*)d_in[2], (const float*)d_in[3],
      (const float*)d_in[4], (const float*)d_in[5],
      (const float*)d_in[6], (const float*)d_in[7],
      (const float*)d_in[8], (const float*)d_in[9],
      (float*)d_out);
}

// Round 12
// 124.433 us; speedup vs baseline: 1.6634x; 1.1566x over previous
//
#include <hip/hip_runtime.h>

typedef __attribute__((ext_vector_type(8))) short bf16x8;
typedef __attribute__((ext_vector_type(4))) float f32x4;
typedef __attribute__((ext_vector_type(4))) unsigned short u16x4;

#define HW_ 16384
#define LDSTR 144     // 72 bf16 elems * 2B per LDS row
#define TILEB 9216    // one 64-pixel x 64-channel bf16 tile

__device__ __forceinline__ float bf2f(unsigned short u) {
  union { unsigned u; float f; } x; x.u = ((unsigned)u) << 16; return x.f;
}
__device__ __forceinline__ unsigned short f2bf(float f) {
  union { float f; unsigned u; } x; x.f = f;
  unsigned r = x.u + 0x7fffu + ((x.u >> 16) & 1u);
  return (unsigned short)(r >> 16);
}
// XOR-swizzled LDS byte offset for transposed tile xT[px][ch]
__device__ __forceinline__ int swz(int row, int cb) {
  return row * LDSTR + (cb ^ (((row >> 3) & 7) << 4));
}

#define MFMA(a, b, c) __builtin_amdgcn_mfma_f32_16x16x32_bf16(a, b, c, 0, 0, 0)

// (256,3): R8-proven. (256,4) spills (R9: unified VGPR+AGPR demand ~140 > 128
// cap -> WRITE_SIZE +172MB scratch). R11 showed occupancy >30% buys nothing,
// so stay at the no-spill 3-waves/SIMD point.
__global__ __launch_bounds__(256, 3) void gci_kernel(
    const float* __restrict__ x1, const float* __restrict__ x2,
    const float* __restrict__ x3, const float* __restrict__ x4,
    const float* __restrict__ wI, const float* __restrict__ bI,
    const float* __restrict__ wS, const float* __restrict__ bS,
    const float* __restrict__ wG, const float* __restrict__ bG,
    float* __restrict__ out)
{
  // 4 tiles of [64 px][72 bf16]: xT0..xT3 (36864 B)
  __shared__ __align__(16) char ldsb[4 * TILEB];

  const int t    = threadIdx.x;
  const int lane = t & 63;
  const int w    = t >> 6;       // wave id == output-channel group (16 ch)
  const int lr   = lane & 15;
  const int lg   = lane >> 4;

  const int pix0 = blockIdx.x * 64;
  const int b    = pix0 >> 14;          // image index (HW = 16384)
  const int pimg = pix0 & (HW_ - 1);    // pixel offset within image

  const float* xin[4] = {x1, x2, x3, x4};

  // ---------- stage x1..x4 transposed (bf16) into LDS (R8-proven) ----------
  #pragma unroll
  for (int ch2 = 0; ch2 < 4; ++ch2) {
    const int q  = ch2 * 256 + t;       // 1024 chunks: 64 ch x 16 px-quads
    const int c  = q >> 4;
    const int p4 = q & 15;
    const int goff = (b * 64 + c) * HW_ + pimg + p4 * 4;
    #pragma unroll
    for (int i = 0; i < 4; ++i) {
      f32x4 v = *reinterpret_cast<const f32x4*>(xin[i] + goff);
      #pragma unroll
      for (int j = 0; j < 4; ++j)
        *(unsigned short*)(ldsb + i * TILEB + swz(p4 * 4 + j, c * 2)) = f2bf(v[j]);
    }
  }

  // ---------- this wave's weights: 16 output channels (rows w*16..+15) ----------
  // A-frag(kk): lane holds W[w*16 + lr][kk*32 + lg*8 + j], j=0..7
  bf16x8 fWi[2], fD[2], fG1[2], fG2[2];
  #pragma unroll
  for (int kk = 0; kk < 2; ++kk) {
    const int row = w * 16 + lr, col = kk * 32 + lg * 8;
    f32x4 wa = *(const f32x4*)(wI + row * 64 + col);
    f32x4 wb = *(const f32x4*)(wI + row * 64 + col + 4);
    f32x4 sa = *(const f32x4*)(wS + row * 64 + col);
    f32x4 sb = *(const f32x4*)(wS + row * 64 + col + 4);
    f32x4 ga = *(const f32x4*)(wG + row * 128 + col);
    f32x4 gb = *(const f32x4*)(wG + row * 128 + col + 4);
    f32x4 ha = *(const f32x4*)(wG + row * 128 + 64 + col);
    f32x4 hb = *(const f32x4*)(wG + row * 128 + 64 + col + 4);
    #pragma unroll
    for (int j = 0; j < 4; ++j) {
      fWi[kk][j]     = (short)f2bf(wa[j]);
      fWi[kk][j + 4] = (short)f2bf(wb[j]);
      fD[kk][j]      = (short)f2bf(sa[j] - wa[j]);
      fD[kk][j + 4]  = (short)f2bf(sb[j] - wb[j]);
      fG1[kk][j]     = (short)f2bf(ga[j]);
      fG1[kk][j + 4] = (short)f2bf(gb[j]);
      fG2[kk][j]     = (short)f2bf(ha[j]);
      fG2[kk][j + 4] = (short)f2bf(hb[j]);
    }
  }

  // biases: C/D row = lg*4 + r  ->  ch = w*16 + lg*4 + r
  f32x4 biasA0, biasG;
  #pragma unroll
  for (int r = 0; r < 4; ++r) {
    const int ch = w * 16 + lg * 4 + r;
    biasA0[r] = bS[ch] + 3.f * bI[ch];
    biasG[r]  = bG[ch];
  }

  __syncthreads();

  // ---------- Abase[g] = Sum_i Wi*x_i + bias, via MFMA (no VALU unpack-sum) ----------
  f32x4 Abase[4];
  #pragma unroll
  for (int g = 0; g < 4; ++g) {
    Abase[g] = biasA0;
    #pragma unroll
    for (int i = 0; i < 4; ++i) {
      #pragma unroll
      for (int kk = 0; kk < 2; ++kk) {
        bf16x8 f = *(const bf16x8*)(ldsb + i * TILEB + swz(g * 16 + lr, kk * 64 + lg * 16));
        Abase[g] = MFMA(fWi[kk], f, Abase[g]);
      }
    }
  }

  // ---------- per tensor: agg + gate + residual + store ----------
  #pragma unroll
  for (int i = 0; i < 4; ++i) {
    char* tb = ldsb + i * TILEB;

    // B-frags for all 4 px-groups (held across agg AND gate; tile is overwritten)
    bf16x8 xB[4][2];
    #pragma unroll
    for (int g = 0; g < 4; ++g)
      #pragma unroll
      for (int kk = 0; kk < 2; ++kk)
        xB[g][kk] = *(const bf16x8*)(tb + swz(g * 16 + lr, kk * 64 + lg * 16));

    // residual pre-read: lane = px, channels (w*16+2j, w*16+2j+1)
    unsigned xrp[8];
    #pragma unroll
    for (int j = 0; j < 8; ++j)
      xrp[j] = *(const unsigned*)(tb + swz(lane, w * 32 + 4 * j));

    // agg = relu(D * x_i + Abase)
    f32x4 agg[4];
    #pragma unroll
    for (int g = 0; g < 4; ++g) {
      agg[g] = Abase[g];
      #pragma unroll
      for (int kk = 0; kk < 2; ++kk) agg[g] = MFMA(fD[kk], xB[g][kk], agg[g]);
    }

    __syncthreads();   // all waves done reading x-tile i

    // write relu(agg) bf16 over tile i: our 16 ch columns, all px rows
    #pragma unroll
    for (int g = 0; g < 4; ++g) {
      u16x4 pk;
      #pragma unroll
      for (int r = 0; r < 4; ++r) pk[r] = f2bf(fmaxf(agg[g][r], 0.f));
      *(u16x4*)(tb + swz(g * 16 + lr, w * 32 + lg * 8)) = pk;
    }

    __syncthreads();   // aggT complete (all 64 channels)

    // gate: out = x + Wg1*x + Wg2*agg + b_gate
    f32x4 og[4];
    #pragma unroll
    for (int g = 0; g < 4; ++g) {
      bf16x8 aB[2];
      #pragma unroll
      for (int kk = 0; kk < 2; ++kk)
        aB[kk] = *(const bf16x8*)(tb + swz(g * 16 + lr, kk * 64 + lg * 16));
      og[g] = biasG;
      #pragma unroll
      for (int kk = 0; kk < 2; ++kk) {
        og[g] = MFMA(fG1[kk], xB[g][kk], og[g]);
        og[g] = MFMA(fG2[kk], aB[kk], og[g]);
      }
    }

    // ---- butterfly 4x4 (lg <-> g) transpose: B[r][v] at lane(lg,lr) =
    // og[lg][r] of lane(v,lr). Replaces 64 ds_bpermute/tensor with 16 shfl_xor.
    float B[4][4];
    #pragma unroll
    for (int r = 0; r < 4; ++r) {
      float X0 = og[0][r], X1 = og[1][r], X2 = og[2][r], X3 = og[3][r];
      float s01 = (lg & 1) ? X0 : X1; s01 = __shfl_xor(s01, 16, 64);
      float n0  = (lg & 1) ? s01 : X0;
      float n1  = (lg & 1) ? X1  : s01;
      float s23 = (lg & 1) ? X2 : X3; s23 = __shfl_xor(s23, 16, 64);
      float n2  = (lg & 1) ? s23 : X2;
      float n3  = (lg & 1) ? X3  : s23;
      float u02 = (lg & 2) ? n0 : n2; u02 = __shfl_xor(u02, 32, 64);
      B[r][0]   = (lg & 2) ? u02 : n0;
      B[r][2]   = (lg & 2) ? n2  : u02;
      float u13 = (lg & 2) ? n1 : n3; u13 = __shfl_xor(u13, 32, 64);
      B[r][1]   = (lg & 2) ? u13 : n1;
      B[r][3]   = (lg & 2) ? n3  : u13;
    }

    // stores: one instruction = 64 consecutive px (256 B lines)
    const int obase0 = i * 16777216 + b * 64 * HW_ + pimg;
    #pragma unroll
    for (int c = 0; c < 16; ++c) {
      float v = B[c & 3][c >> 2]
              + bf2f((unsigned short)(xrp[c >> 1] >> ((c & 1) * 16)));
      out[obase0 + (w * 16 + c) * HW_ + lane] = v;
    }
  }
}

extern "C" void kernel_launch(void* const* d_in, const int* in_sizes, int n_in,
                              void* d_out, int out_size, void* d_ws, size_t ws_size,
                              hipStream_t stream) {
  (void)in_sizes; (void)n_in; (void)d_ws; (void)ws_size; (void)out_size;
  gci_kernel<<<dim3(4096), dim3(256), 0, stream>>>(
      (const float*)d_in[0], (const float*)d_in[1],
      (const float*)d_in[2], (const float*)d_in[3],
      (const float*)d_in[4], (const float*)d_in[5],
      (const float*)d_in[6], (const float*)d_in[7],
      (const float*)d_in[8], (const float*)d_in[9],
      (float*)d_out);
}

// Round 13
// 123.317 us; speedup vs baseline: 1.6784x; 1.0091x over previous
//
#include <hip/hip_runtime.h>

typedef __attribute__((ext_vector_type(8))) short bf16x8;
typedef __attribute__((ext_vector_type(4))) float f32x4;
typedef __attribute__((ext_vector_type(4))) unsigned short u16x4;

#define HW_ 16384
#define LDSTR 144     // 72 bf16 elems * 2B per LDS row
#define TILEB 9216    // one 64-pixel x 64-channel bf16 tile

__device__ __forceinline__ float bf2f(unsigned short u) {
  union { unsigned u; float f; } x; x.u = ((unsigned)u) << 16; return x.f;
}
__device__ __forceinline__ unsigned short f2bf(float f) {
  union { float f; unsigned u; } x; x.f = f;
  unsigned r = x.u + 0x7fffu + ((x.u >> 16) & 1u);
  return (unsigned short)(r >> 16);
}
// XOR-swizzled LDS byte offset for transposed tile xT[px][ch]
__device__ __forceinline__ int swz(int row, int cb) {
  return row * LDSTR + (cb ^ (((row >> 3) & 7) << 4));
}

#define MFMA(a, b, c) __builtin_amdgcn_mfma_f32_16x16x32_bf16(a, b, c, 0, 0, 0)

// (256,3): R8-proven no-spill point (R9: (256,4) -> unified demand ~140 > 128
// cap -> scratch spill). R11: occupancy >30% alone buys nothing; the limiter
// is loads-in-flight per wave (MLP), addressed by the issue-all-16 staging.
__global__ __launch_bounds__(256, 3) void gci_kernel(
    const float* __restrict__ x1, const float* __restrict__ x2,
    const float* __restrict__ x3, const float* __restrict__ x4,
    const float* __restrict__ wI, const float* __restrict__ bI,
    const float* __restrict__ wS, const float* __restrict__ bS,
    const float* __restrict__ wG, const float* __restrict__ bG,
    float* __restrict__ out)
{
  // 4 tiles of [64 px][72 bf16]: xT0..xT3 (36864 B)
  __shared__ __align__(16) char ldsb[4 * TILEB];

  const int t    = threadIdx.x;
  const int lane = t & 63;
  const int w    = t >> 6;       // wave id == output-channel group (16 ch)
  const int lr   = lane & 15;
  const int lg   = lane >> 4;

  const int pix0 = blockIdx.x * 64;
  const int b    = pix0 >> 14;          // image index (HW = 16384)
  const int pimg = pix0 & (HW_ - 1);    // pixel offset within image

  const float* xin[4] = {x1, x2, x3, x4};

  // ---------- stage x1..x4 transposed (bf16) into LDS ----------
  // MLP fix: issue ALL 16 global_load_dwordx4 back-to-back (statically-indexed
  // v[16] stays in regs), THEN cvt+scatter. Compiler drains vmcnt progressively,
  // overlapping cvt/ds_write of early loads with remaining load returns.
  f32x4 v[16];
  #pragma unroll
  for (int ch2 = 0; ch2 < 4; ++ch2) {
    const int q  = ch2 * 256 + t;       // 1024 chunks: 64 ch x 16 px-quads
    const int c  = q >> 4;
    const int p4 = q & 15;
    const int goff = (b * 64 + c) * HW_ + pimg + p4 * 4;
    #pragma unroll
    for (int i = 0; i < 4; ++i)
      v[ch2 * 4 + i] = *reinterpret_cast<const f32x4*>(xin[i] + goff);
  }
  #pragma unroll
  for (int ch2 = 0; ch2 < 4; ++ch2) {
    const int q  = ch2 * 256 + t;
    const int c  = q >> 4;
    const int p4 = q & 15;
    #pragma unroll
    for (int i = 0; i < 4; ++i) {
      #pragma unroll
      for (int j = 0; j < 4; ++j)
        *(unsigned short*)(ldsb + i * TILEB + swz(p4 * 4 + j, c * 2)) =
            f2bf(v[ch2 * 4 + i][j]);
    }
  }

  // ---------- this wave's weights: 16 output channels (rows w*16..+15) ----------
  // A-frag(kk): lane holds W[w*16 + lr][kk*32 + lg*8 + j], j=0..7
  bf16x8 fWi[2], fD[2], fG1[2], fG2[2];
  #pragma unroll
  for (int kk = 0; kk < 2; ++kk) {
    const int row = w * 16 + lr, col = kk * 32 + lg * 8;
    f32x4 wa = *(const f32x4*)(wI + row * 64 + col);
    f32x4 wb = *(const f32x4*)(wI + row * 64 + col + 4);
    f32x4 sa = *(const f32x4*)(wS + row * 64 + col);
    f32x4 sb = *(const f32x4*)(wS + row * 64 + col + 4);
    f32x4 ga = *(const f32x4*)(wG + row * 128 + col);
    f32x4 gb = *(const f32x4*)(wG + row * 128 + col + 4);
    f32x4 ha = *(const f32x4*)(wG + row * 128 + 64 + col);
    f32x4 hb = *(const f32x4*)(wG + row * 128 + 64 + col + 4);
    #pragma unroll
    for (int j = 0; j < 4; ++j) {
      fWi[kk][j]     = (short)f2bf(wa[j]);
      fWi[kk][j + 4] = (short)f2bf(wb[j]);
      fD[kk][j]      = (short)f2bf(sa[j] - wa[j]);
      fD[kk][j + 4]  = (short)f2bf(sb[j] - wb[j]);
      fG1[kk][j]     = (short)f2bf(ga[j]);
      fG1[kk][j + 4] = (short)f2bf(gb[j]);
      fG2[kk][j]     = (short)f2bf(ha[j]);
      fG2[kk][j + 4] = (short)f2bf(hb[j]);
    }
  }

  // biases: C/D row = lg*4 + r  ->  ch = w*16 + lg*4 + r
  f32x4 biasA0, biasG;
  #pragma unroll
  for (int r = 0; r < 4; ++r) {
    const int ch = w * 16 + lg * 4 + r;
    biasA0[r] = bS[ch] + 3.f * bI[ch];
    biasG[r]  = bG[ch];
  }

  __syncthreads();

  // ---------- Abase[g] = Sum_i Wi*x_i + bias, via MFMA (no VALU unpack-sum) ----------
  f32x4 Abase[4];
  #pragma unroll
  for (int g = 0; g < 4; ++g) {
    Abase[g] = biasA0;
    #pragma unroll
    for (int i = 0; i < 4; ++i) {
      #pragma unroll
      for (int kk = 0; kk < 2; ++kk) {
        bf16x8 f = *(const bf16x8*)(ldsb + i * TILEB + swz(g * 16 + lr, kk * 64 + lg * 16));
        Abase[g] = MFMA(fWi[kk], f, Abase[g]);
      }
    }
  }

  // ---------- per tensor: agg + gate + residual + store ----------
  #pragma unroll
  for (int i = 0; i < 4; ++i) {
    char* tb = ldsb + i * TILEB;

    // B-frags for all 4 px-groups (held across agg AND gate; tile is overwritten)
    bf16x8 xB[4][2];
    #pragma unroll
    for (int g = 0; g < 4; ++g)
      #pragma unroll
      for (int kk = 0; kk < 2; ++kk)
        xB[g][kk] = *(const bf16x8*)(tb + swz(g * 16 + lr, kk * 64 + lg * 16));

    // residual pre-read: lane = px, channels (w*16+2j, w*16+2j+1)
    unsigned xrp[8];
    #pragma unroll
    for (int j = 0; j < 8; ++j)
      xrp[j] = *(const unsigned*)(tb + swz(lane, w * 32 + 4 * j));

    // agg = relu(D * x_i + Abase)
    f32x4 agg[4];
    #pragma unroll
    for (int g = 0; g < 4; ++g) {
      agg[g] = Abase[g];
      #pragma unroll
      for (int kk = 0; kk < 2; ++kk) agg[g] = MFMA(fD[kk], xB[g][kk], agg[g]);
    }

    __syncthreads();   // all waves done reading x-tile i

    // write relu(agg) bf16 over tile i: our 16 ch columns, all px rows
    #pragma unroll
    for (int g = 0; g < 4; ++g) {
      u16x4 pk;
      #pragma unroll
      for (int r = 0; r < 4; ++r) pk[r] = f2bf(fmaxf(agg[g][r], 0.f));
      *(u16x4*)(tb + swz(g * 16 + lr, w * 32 + lg * 8)) = pk;
    }

    __syncthreads();   // aggT complete (all 64 channels)

    // gate: out = x + Wg1*x + Wg2*agg + b_gate
    f32x4 og[4];
    #pragma unroll
    for (int g = 0; g < 4; ++g) {
      bf16x8 aB[2];
      #pragma unroll
      for (int kk = 0; kk < 2; ++kk)
        aB[kk] = *(const bf16x8*)(tb + swz(g * 16 + lr, kk * 64 + lg * 16));
      og[g] = biasG;
      #pragma unroll
      for (int kk = 0; kk < 2; ++kk) {
        og[g] = MFMA(fG1[kk], xB[g][kk], og[g]);
        og[g] = MFMA(fG2[kk], aB[kk], og[g]);
      }
    }

    // ---- butterfly 4x4 (lg <-> g) transpose: B[r][v] at lane(lg,lr) =
    // og[lg][r] of lane(v,lr). 16 shfl_xor per tensor.
    float B[4][4];
    #pragma unroll
    for (int r = 0; r < 4; ++r) {
      float X0 = og[0][r], X1 = og[1][r], X2 = og[2][r], X3 = og[3][r];
      float s01 = (lg & 1) ? X0 : X1; s01 = __shfl_xor(s01, 16, 64);
      float n0  = (lg & 1) ? s01 : X0;
      float n1  = (lg & 1) ? X1  : s01;
      float s23 = (lg & 1) ? X2 : X3; s23 = __shfl_xor(s23, 16, 64);
      float n2  = (lg & 1) ? s23 : X2;
      float n3  = (lg & 1) ? X3  : s23;
      float u02 = (lg & 2) ? n0 : n2; u02 = __shfl_xor(u02, 32, 64);
      B[r][0]   = (lg & 2) ? u02 : n0;
      B[r][2]   = (lg & 2) ? n2  : u02;
      float u13 = (lg & 2) ? n1 : n3; u13 = __shfl_xor(u13, 32, 64);
      B[r][1]   = (lg & 2) ? u13 : n1;
      B[r][3]   = (lg & 2) ? n3  : u13;
    }

    // stores: one instruction = 64 consecutive px (256 B lines)
    const int obase0 = i * 16777216 + b * 64 * HW_ + pimg;
    #pragma unroll
    for (int c = 0; c < 16; ++c) {
      float vv = B[c & 3][c >> 2]
               + bf2f((unsigned short)(xrp[c >> 1] >> ((c & 1) * 16)));
      out[obase0 + (w * 16 + c) * HW_ + lane] = vv;
    }
  }
}

extern "C" void kernel_launch(void* const* d_in, const int* in_sizes, int n_in,
                              void* d_out, int out_size, void* d_ws, size_t ws_size,
                              hipStream_t stream) {
  (void)in_sizes; (void)n_in; (void)d_ws; (void)ws_size; (void)out_size;
  gci_kernel<<<dim3(4096), dim3(256), 0, stream>>>(
      (const float*)d_in[0], (const float*)d_in[1],
      (const float*)d_in[2], (const float*)d_in[3],
      (const float*)d_in[4], (const float*)d_in[5],
      (const float*)d_in[6], (const float*)d_in[7],
      (const float*)d_in[8], (const float*)d_in[9],
      (float*)d_out);
}